// Round 13
// baseline (1666.299 us; speedup 1.0000x reference)
//
#include <hip/hip_runtime.h>

typedef unsigned int   u32;
typedef unsigned long long u64;
typedef float pkf2 __attribute__((ext_vector_type(2)));

#define B_  16
#define N_  8192
#define S_  1024
#define NS_ 32
#define XS_ 68   // [n][c] LDS row stride in floats

__device__ __forceinline__ float nanguard(float v) {
  u32 x = __float_as_uint(v);
  if ((x & 0x7F80u) == 0x7F80u) x ^= 0x0080u;
  return __uint_as_float(x);
}

// wave64 max via DPP (rocPRIM pattern)
__device__ __forceinline__ float wave_max_nonneg(float v) {
  int x = __float_as_int(v);
#define DPP_STEP(ctrl) \
  x = __float_as_int(fmaxf(__int_as_float(x), \
      __int_as_float(__builtin_amdgcn_update_dpp(0, x, (ctrl), 0xf, 0xf, true))))
  DPP_STEP(0x111);  // row_shr:1
  DPP_STEP(0x112);  // row_shr:2
  DPP_STEP(0x114);  // row_shr:4
  DPP_STEP(0x118);  // row_shr:8
  DPP_STEP(0x142);  // row_bcast15
  DPP_STEP(0x143);  // row_bcast31
#undef DPP_STEP
  return __int_as_float(__builtin_amdgcn_readlane(x, 63));
}

// ---------------- K0a: xyz (B,3,N) -> (B,N,4) f32 ----------------
__global__ __launch_bounds__(256) void k_xyzt(const float* __restrict__ xyz, float4* __restrict__ xyzt) {
  int b = blockIdx.y;
  int i = blockIdx.x * 256 + threadIdx.x;
  const float* p = xyz + (size_t)b * 3 * N_;
  xyzt[(size_t)b * N_ + i] = make_float4(p[i], p[N_ + i], p[2 * N_ + i], 0.f);
}

// ---------------- K0b: points (B,64,N) -> (B,N,64) f32 ----------------
__global__ __launch_bounds__(256) void k_ptst(const float* __restrict__ pts, float* __restrict__ ptst) {
  __shared__ float tile[64][65];
  int b = blockIdx.y, n0 = blockIdx.x * 64, t = threadIdx.x;
  {
    int c = t >> 2, j0 = (t & 3) * 16;
    const float4* src = (const float4*)(pts + (size_t)b * 64 * N_ + (size_t)c * N_ + n0 + j0);
#pragma unroll
    for (int q = 0; q < 4; ++q) {
      float4 a = src[q];
      tile[c][j0 + 4*q + 0] = a.x; tile[c][j0 + 4*q + 1] = a.y;
      tile[c][j0 + 4*q + 2] = a.z; tile[c][j0 + 4*q + 3] = a.w;
    }
  }
  __syncthreads();
  {
    int n = t >> 2, c0 = (t & 3) * 16;
    float4* dv = (float4*)(ptst + ((size_t)b * N_ + n0 + n) * 64 + c0);
#pragma unroll
    for (int q = 0; q < 4; ++q)
      dv[q] = make_float4(tile[c0 + 4*q + 0][n], tile[c0 + 4*q + 1][n],
                          tile[c0 + 4*q + 2][n], tile[c0 + 4*q + 3][n]);
  }
}

// ---------------- K1: furthest point sampling ----------------
// r13: NO ATOMICS. r12 counters falsified VALU-issue and centroid-load
// theories (pk halved dist-update slots, VALUBusy 5.13->4.75%, time flat);
// the remaining critical-path giant is 16 same-address LDS atomicMax RMWs
// serializing ~1000+cyc/iter. Replace with: plain per-wave candidate store
// (double-buffered cand[2][16]) + redundant 16-way reduce in every wave
// (one ds_read_b64 + DPP max + ballot). Tie-break stays exact: contiguous
// ownership => smaller wave id = smaller global indices; ffs picks it.
__global__ __launch_bounds__(1024)
__attribute__((amdgpu_waves_per_eu(4, 4)))
void k_fps(const float4* __restrict__ xyzt,
           float4* __restrict__ nxf,
           float* __restrict__ out_xyz) {
#pragma clang fp contract(off)
  __shared__ float4 ldsp[N_];       // 128 KB coord cache
  __shared__ u64 cand[2][16];       // double-buffered per-wave candidates
  __shared__ int win_hist[S_];
  int b = blockIdx.x, t = threadIdx.x;
  int lane = t & 63, wid = t >> 6;
  const float4* p4 = xyzt + (size_t)b * N_;
  const float4* pp8 = p4 + t * 8;

  float4 q0 = pp8[0], q1 = pp8[1], q2 = pp8[2], q3 = pp8[3];
  float4 q4 = pp8[4], q5 = pp8[5], q6 = pp8[6], q7 = pp8[7];
  ldsp[t * 8 + 0] = q0; ldsp[t * 8 + 1] = q1; ldsp[t * 8 + 2] = q2; ldsp[t * 8 + 3] = q3;
  ldsp[t * 8 + 4] = q4; ldsp[t * 8 + 5] = q5; ldsp[t * 8 + 6] = q6; ldsp[t * 8 + 7] = q7;

#define DECLPAIR(P, A, B) \
  pkf2 px##P = {q##A.x, q##B.x}; pkf2 py##P = {q##A.y, q##B.y}; \
  pkf2 pz##P = {q##A.z, q##B.z}; pkf2 dm##P = {1e10f, 1e10f};
  DECLPAIR(01, 0, 1) DECLPAIR(23, 2, 3) DECLPAIR(45, 4, 5) DECLPAIR(67, 6, 7)
#undef DECLPAIR
#define PIN(P) asm volatile("" : "+v"(px##P), "+v"(py##P), "+v"(pz##P));
  PIN(01) PIN(23) PIN(45) PIN(67)
#undef PIN

  if (t == 0) {
    // "iter 0" winner = index 0: give wave 0 dist 1.0, rest 0
    cand[0][0] = ((u64)__float_as_uint(1.0f) << 32);
#pragma unroll
    for (int j = 1; j < 16; ++j) cand[0][j] = 0;
    cand[1][0] = 0;   // init second buffer head (not strictly needed)
  }
  __syncthreads();
  for (int it = 1; it < S_; ++it) {
    // --- redundant 16-way reduce of previous iteration's candidates ---
    u64 cv = cand[(it - 1) & 1][lane & 15];     // 4-fold broadcast read
    float cd = __uint_as_float((u32)(cv >> 32));
    int   ci = (int)(cv & 0xFFFFFFFFull);
    float cm = wave_max_nonneg(cd);
    u64 cmsk = __ballot(cd == cm);
    int cl = __ffsll((long long)cmsk) - 1;      // smallest lane = smallest wave
    int widx = __builtin_amdgcn_readlane(ci, cl) & (N_ - 1);
    if (t == 0) win_hist[it - 1] = widx;
    float4 c = ldsp[widx];                       // LDS broadcast
    pkf2 cx2 = {c.x, c.x}, cy2 = {c.y, c.y}, cz2 = {c.z, c.z};
    // exact np order per element: (dx*dx + dy*dy) + dz*dz, RNE each op
#define UPDP(P) { \
    pkf2 dx = px##P - cx2; pkf2 dy = py##P - cy2; pkf2 dz = pz##P - cz2; \
    pkf2 xx = dx * dx; pkf2 yy = dy * dy; pkf2 zz = dz * dz; \
    pkf2 ss = xx + yy; pkf2 dd = ss + zz; \
    dm##P.x = fminf(dm##P.x, dd.x); dm##P.y = fminf(dm##P.y, dd.y); }
    UPDP(01) UPDP(23) UPDP(45) UPDP(67)
#undef UPDP
    float e0 = dm01.x, e1 = dm01.y, e2 = dm23.x, e3 = dm23.y;
    float e4 = dm45.x, e5 = dm45.y, e6 = dm67.x, e7 = dm67.y;
    // pairwise tree, strict > so ties keep lower k
    float va0 = e1 > e0 ? e1 : e0; int ia0 = e1 > e0 ? 1 : 0;
    float va1 = e3 > e2 ? e3 : e2; int ia1 = e3 > e2 ? 3 : 2;
    float va2 = e5 > e4 ? e5 : e4; int ia2 = e5 > e4 ? 5 : 4;
    float va3 = e7 > e6 ? e7 : e6; int ia3 = e7 > e6 ? 7 : 6;
    float vb0 = va1 > va0 ? va1 : va0; int ib0 = va1 > va0 ? ia1 : ia0;
    float vb1 = va3 > va2 ? va3 : va2; int ib1 = va3 > va2 ? ia3 : ia2;
    float bv = vb1 > vb0 ? vb1 : vb0;  int bk = vb1 > vb0 ? ib1 : ib0;
    int bi = t * 8 + bk;
    // wave argmax: DPP max + first lane holding it (== smallest idx)
    float wm = wave_max_nonneg(bv);
    u64 msk = __ballot(bv == wm);
    int wl = __ffsll((long long)msk) - 1;
    int wbi = __builtin_amdgcn_readlane(bi, wl);
    if (lane == 0)
      cand[it & 1][wid] = ((u64)__float_as_uint(wm) << 32) | (u64)(u32)wbi;
    __syncthreads();
  }
  { // final winner (iteration S_-1's candidates)
    u64 cv = cand[(S_ - 1) & 1][lane & 15];
    float cd = __uint_as_float((u32)(cv >> 32));
    int   ci = (int)(cv & 0xFFFFFFFFull);
    float cm = wave_max_nonneg(cd);
    u64 cmsk = __ballot(cd == cm);
    int cl = __ffsll((long long)cmsk) - 1;
    if (t == 0) win_hist[S_ - 1] = __builtin_amdgcn_readlane(ci, cl) & (N_ - 1);
  }
  __syncthreads();
  {
    int wi = win_hist[t] & (N_ - 1);
    float4 c = ldsp[wi];
    nxf[(size_t)b * S_ + t] = c;
    float* o = out_xyz + (size_t)b * 3 * S_;
    o[t] = nanguard(c.x); o[S_ + t] = nanguard(c.y); o[2 * S_ + t] = nanguard(c.z);
  }
}

// ---------------- K2: ball query (first 32 in range, ascending) ----------------
__global__ __launch_bounds__(256) void k_ball(const float4* __restrict__ xyzt,
                                              const float4* __restrict__ nxf,
                                              int* __restrict__ ballidx) {
  int gw = blockIdx.x * 4 + (threadIdx.x >> 6);
  int lane = threadIdx.x & 63;
  int b = gw >> 10, s = gw & 1023;
  float4 c = nxf[(size_t)b * S_ + s];
  const float4* pts = xyzt + (size_t)b * N_;
  int* out = ballidx + (size_t)gw * NS_;
  int cnt = 0, first = 0;
  bool havefirst = false;
  for (int chunk = 0; chunk < N_; chunk += 64) {
    float4 p = pts[chunk + lane];
    float dx = p.x - c.x, dy = p.y - c.y, dz = p.z - c.z;
    float d2 = __fadd_rn(__fadd_rn(__fmul_rn(dx, dx), __fmul_rn(dy, dy)), __fmul_rn(dz, dz));
    bool v = d2 <= 0.04f;
    u64 m = __ballot(v);
    if (m) {
      int pos = cnt + __popcll(m & ((1ull << lane) - 1ull));
      if (v && pos < NS_) out[pos] = chunk + lane;
      if (!havefirst) { first = chunk + (__ffsll((long long)m) - 1); havefirst = true; }
      cnt += __popcll(m);
      if (cnt >= NS_) break;
    }
  }
  if (cnt < NS_) {
    for (int p = cnt + lane; p < NS_; p += 64) out[p] = first;
  }
}

// ---------------- chain machinery: [n][c], single weight slot, in-place X ----
struct ChainSm {
  float Wbuf[64 * XS_];                       // staged: w2 -> m0w -> m1w
  float W1f[64 * 9];
  float W0f[8 * 4];
  float s2f[64], sm0f[64], sm1f[64];
  float bb0[8];
  float bb1[64], bb2[64], bm0[64], bm1[64];
  float X[32 * XS_];                          // [n][c]
  float scratch[384];                         // P8 [0,256), GX [256,384); psum overlay
  int   idx_s[NS_];
};

__device__ __forceinline__ void stage_w64(float* Wbuf, const float* w, int t) {
  int c = t >> 2, q = (t & 3) * 16;
  const float4* src = (const float4*)(w + c * 64 + q);
  float4* dst = (float4*)(Wbuf + c * XS_ + q);
  dst[0] = src[0]; dst[1] = src[1]; dst[2] = src[2]; dst[3] = src[3];
}

// one 64x64 GEMM pass over the wave's 8 n-rows, in-place allowed
template<bool RELU>
__device__ __forceinline__ void gemm64(const float* Wbuf, float* Xb,
                                       const float* scl, const float* bia,
                                       int lane, int n0) {
  float acc[8] = {0,0,0,0,0,0,0,0};
#pragma unroll
  for (int k4 = 0; k4 < 16; ++k4) {
    float4 wq = *(const float4*)&Wbuf[lane * XS_ + k4 * 4];
#pragma unroll
    for (int nj = 0; nj < 8; ++nj) {
      float4 xq = *(const float4*)&Xb[(n0 + nj) * XS_ + k4 * 4];
      acc[nj] += wq.x * xq.x; acc[nj] += wq.y * xq.y;
      acc[nj] += wq.z * xq.z; acc[nj] += wq.w * xq.w;
    }
  }
  float sc = scl[lane], bi = bia[lane];
#pragma unroll
  for (int nj = 0; nj < 8; ++nj) {
    float v = sc * acc[nj] + bi;
    Xb[(n0 + nj) * XS_ + lane] = RELU ? fmaxf(v, 0.f) : v;
  }
}

// chain through mlp1: post-relu f32 result left in sm.X ([n][c])
template<bool USE_PTST>
__device__ __forceinline__ void chain_tile(ChainSm& sm, int b, int s, int bs,
    const float4* xyzt, const float* ptst, const float* points,
    const float4* nxf, const int* ballidx,
    const float* w0, const float* b0, const float* s0, const float* t0,
    const float* w1, const float* b1, const float* s1, const float* t1,
    const float* w2, const float* b2, const float* s2, const float* t2,
    const float* m0w, const float* m0b, const float* m0s, const float* m0t,
    const float* m1w, const float* m1b, const float* m1s, const float* m1t) {
  int t = threadIdx.x, lane = t & 63, g = t >> 6, n0 = g * 8;

  stage_w64(sm.Wbuf, w2, t);
  if (t < 64) {
    float v2 = s2[t];  sm.s2f[t] = v2;  sm.bb2[t] = v2 * b2[t] + t2[t];
    float vm0 = m0s[t]; sm.sm0f[t] = vm0; sm.bm0[t] = vm0 * m0b[t] + m0t[t];
    float vm1 = m1s[t]; sm.sm1f[t] = vm1; sm.bm1[t] = vm1 * m1b[t] + m1t[t];
    float v1 = s1[t];
#pragma unroll
    for (int k = 0; k < 8; ++k) sm.W1f[t * 9 + k] = v1 * w1[t * 8 + k];
    sm.bb1[t] = v1 * b1[t] + t1[t];
  }
  if (t < 8) {
    float v0 = s0[t];
#pragma unroll
    for (int k = 0; k < 3; ++k) sm.W0f[t * 4 + k] = v0 * w0[t * 3 + k];
    sm.bb0[t] = v0 * b0[t] + t0[t];
  }
  if (t < NS_) sm.idx_s[t] = ballidx[(size_t)bs * NS_ + t] & (N_ - 1);
  __syncthreads();                                   // B1

  { // gather points -> X[n][c] rows (wave-own)
    int n = t >> 3, c8 = (t & 7) * 8;
    int pi = sm.idx_s[n];
    if (USE_PTST) {
      const float4* v = (const float4*)(ptst + ((size_t)b * N_ + pi) * 64 + c8);
      float4* xr = (float4*)&sm.X[n * XS_ + c8];
      xr[0] = v[0]; xr[1] = v[1];
    } else {
      const float* pp = points + (size_t)b * 64 * N_ + (size_t)c8 * N_ + pi;
#pragma unroll
      for (int j = 0; j < 8; ++j) sm.X[n * XS_ + c8 + j] = pp[(size_t)j * N_];
    }
  }
  if (t < NS_) { // centered xyz -> GX
    float4 p = xyzt[(size_t)b * N_ + sm.idx_s[t]];
    float4 cc = nxf[(size_t)b * S_ + s];
    float* gx = &sm.scratch[256 + t * 4];
    gx[0] = p.x - cc.x; gx[1] = p.y - cc.y; gx[2] = p.z - cc.z;
  }
  __syncthreads();                                   // B2 (GX cross-wave)

  { // conv0 (8 out, K=3) + bn + relu -> P8[n][cc]
    int n = t >> 3, cc = t & 7;
    const float* gx = &sm.scratch[256 + n * 4];
    float a = sm.bb0[cc];
    a += sm.W0f[cc * 4 + 0] * gx[0];
    a += sm.W0f[cc * 4 + 1] * gx[1];
    a += sm.W0f[cc * 4 + 2] * gx[2];
    sm.scratch[n * 8 + cc] = fmaxf(a, 0.f);
  }
  { // conv1 (64 out, K=8) + bn, residual into X (own rows; no barrier needed)
#pragma unroll
    for (int nj = 0; nj < 8; ++nj) {
      float a = sm.bb1[lane];
      const float* p8 = &sm.scratch[(n0 + nj) * 8];
#pragma unroll
      for (int k = 0; k < 8; ++k) a += sm.W1f[lane * 9 + k] * p8[k];
      sm.X[(n0 + nj) * XS_ + lane] += a;
    }
  }
  gemm64<false>(sm.Wbuf, sm.X, sm.s2f, sm.bb2, lane, n0);   // conv2
  __syncthreads();                                   // B3 (done reading w2)
  stage_w64(sm.Wbuf, m0w, t);
  __syncthreads();                                   // B4
  gemm64<true>(sm.Wbuf, sm.X, sm.sm0f, sm.bm0, lane, n0);   // mlp0
  __syncthreads();                                   // B5 (done reading m0w)
  stage_w64(sm.Wbuf, m1w, t);
  __syncthreads();                                   // B6
  gemm64<true>(sm.Wbuf, sm.X, sm.sm1f, sm.bm1, lane, n0);   // mlp1 -> X
}

// ---------------- K3: chain pass -> partials (+ optional h2 f32) ----------------
template<bool USE_PTST, bool WRITE_H2>
__global__ __launch_bounds__(256) void k_chain(
    const float4* __restrict__ xyzt, const float* __restrict__ ptst,
    const float* __restrict__ points,
    const float4* __restrict__ nxf, const int* __restrict__ ballidx,
    const float* w0, const float* b0, const float* s0, const float* t0,
    const float* w1, const float* b1, const float* s1, const float* t1,
    const float* w2, const float* b2, const float* s2, const float* t2,
    const float* m0w, const float* m0b, const float* m0s, const float* m0t,
    const float* m1w, const float* m1b, const float* m1s, const float* m1t,
    float* __restrict__ h2out, float* __restrict__ partials) {
  __shared__ ChainSm sm;
  int t = threadIdx.x, bs = blockIdx.x;
  int b = bs >> 10, s = bs & 1023;
  int lane = t & 63, g = t >> 6, n0 = g * 8;

  chain_tile<USE_PTST>(sm, b, s, bs, xyzt, ptst, points, nxf, ballidx,
                       w0, b0, s0, t0, w1, b1, s1, t1, w2, b2, s2, t2,
                       m0w, m0b, m0s, m0t, m1w, m1b, m1s, m1t);

  float* psum = sm.scratch;   // P8/GX dead (all waves past B3)
  float lsum = 0.f;
#pragma unroll
  for (int nj = 0; nj < 8; ++nj) {
    float r = sm.X[(n0 + nj) * XS_ + lane];
    lsum += r;
    if (WRITE_H2)
      h2out[((size_t)bs * 32 + n0 + nj) * 64 + lane] = r;
  }
  psum[lane * 5 + g] = lsum;
  __syncthreads();                                   // B7
  if (t < 64) {
    float v = (psum[t * 5 + 0] + psum[t * 5 + 1]) + (psum[t * 5 + 2] + psum[t * 5 + 3]);
    partials[(size_t)bs * 64 + t] = v;
  }
}

// ---------------- K4: mean + ECA conv + sigmoid -> sig (B,64) ----------------
__global__ __launch_bounds__(256) void k_eca(const float* __restrict__ partials,
                                             const float* __restrict__ ecak,
                                             float* __restrict__ sig) {
  __shared__ float red[64 * 5];
  __shared__ float yy[66];
  int b = blockIdx.x, t = threadIdx.x;
  int c = t & 63, sg = t >> 6;
  float acc = 0.f;
  for (int s = sg; s < S_; s += 4) acc += partials[((size_t)b * S_ + s) * 64 + c];
  red[c * 5 + sg] = acc;
  __syncthreads();
  if (t < 64) {
    float v = (red[t * 5 + 0] + red[t * 5 + 1]) + (red[t * 5 + 2] + red[t * 5 + 3]);
    yy[t + 1] = v * (1.f / 32768.f);
  }
  if (t == 64) { yy[0] = 0.f; yy[65] = 0.f; }
  __syncthreads();
  if (t < 64) {
    float gv = ecak[0] * yy[t] + ecak[1] * yy[t + 1] + ecak[2] * yy[t + 2];
    sig[b * 64 + t] = 1.f / (1.f + expf(-gv));
  }
}

// one 64-output-row half of the final conv
__device__ __forceinline__ void final_half(const float* W, const float* X2,
                                           const float* esf, const float* bbf,
                                           float* zred, int off, int lane, int g, int n0) {
  float a[8] = {0,0,0,0,0,0,0,0};
#pragma unroll
  for (int k4 = 0; k4 < 16; ++k4) {
    float4 wq = *(const float4*)&W[lane * XS_ + k4 * 4];
#pragma unroll
    for (int nj = 0; nj < 8; ++nj) {
      float4 xq = *(const float4*)&X2[(n0 + nj) * XS_ + k4 * 4];
      a[nj] += wq.x * xq.x; a[nj] += wq.y * xq.y;
      a[nj] += wq.z * xq.z; a[nj] += wq.w * xq.w;
    }
  }
  float m = a[0];
#pragma unroll
  for (int j = 1; j < 8; ++j) m = fmaxf(m, a[j]);
  // bn scale > 0, f32 affine monotone -> affine(max)==max(affine)
  zred[(lane + off) * 5 + g] = esf[lane + off] * m + bbf[lane + off];
}

// ---------------- K5a: fast final (reads stored h2 (bs,n,c)) ----------------
__global__ __launch_bounds__(256) void k_final_h2(const float* __restrict__ h2,
                                                  const float* __restrict__ sig,
                                                  const float* ew, const float* eb,
                                                  const float* es, const float* et,
                                                  float* __restrict__ outf) {
  __shared__ float Wb[64 * XS_];
  __shared__ float X2[32 * XS_];
  __shared__ float zred[128 * 5];
  __shared__ float esf[128], bbf[128], sigl[64];
  int t = threadIdx.x, bs = blockIdx.x;
  int b = bs >> 10, s = bs & 1023;
  int lane = t & 63, g = t >> 6, n0 = g * 8;
  stage_w64(Wb, ew, t);                    // rows 0..63
  if (t < 128) { float v = es[t]; esf[t] = v; bbf[t] = v * eb[t] + et[t]; }
  if (t < 64) sigl[t] = sig[b * 64 + t];
  __syncthreads();
  { // gather + gate -> X2 (own rows)
    int n = t >> 3, c8 = (t & 7) * 8;
    const float4* v = (const float4*)(h2 + ((size_t)bs * 32 + n) * 64 + c8);
    float4 a = v[0], bq = v[1];
    a.x *= sigl[c8 + 0]; a.y *= sigl[c8 + 1]; a.z *= sigl[c8 + 2]; a.w *= sigl[c8 + 3];
    bq.x *= sigl[c8 + 4]; bq.y *= sigl[c8 + 5]; bq.z *= sigl[c8 + 6]; bq.w *= sigl[c8 + 7];
    float4* xr = (float4*)&X2[n * XS_ + c8];
    xr[0] = a; xr[1] = bq;
  }
  final_half(Wb, X2, esf, bbf, zred, 0, lane, g, n0);
  __syncthreads();                          // done reading rows 0..63
  stage_w64(Wb, ew + 64 * 64, t);          // rows 64..127
  __syncthreads();
  final_half(Wb, X2, esf, bbf, zred, 64, lane, g, n0);
  __syncthreads();
  if (t < 128) {
    float m = fmaxf(fmaxf(zred[t * 5 + 0], zred[t * 5 + 1]),
                    fmaxf(zred[t * 5 + 2], zred[t * 5 + 3]));
    outf[((size_t)b * 128 + t) * S_ + s] = nanguard(m);
  }
}

// ---------------- K5b: recompute final (no h2 storage) ----------------
template<bool USE_PTST>
__global__ __launch_bounds__(256) void k_final_rec(
    const float4* __restrict__ xyzt, const float* __restrict__ ptst,
    const float* __restrict__ points,
    const float4* __restrict__ nxf, const int* __restrict__ ballidx,
    const float* w0, const float* b0, const float* s0, const float* t0,
    const float* w1, const float* b1, const float* s1, const float* t1,
    const float* w2, const float* b2, const float* s2, const float* t2,
    const float* m0w, const float* m0b, const float* m0s, const float* m0t,
    const float* m1w, const float* m1b, const float* m1s, const float* m1t,
    const float* __restrict__ sig,
    const float* ew, const float* eb, const float* es, const float* et,
    float* __restrict__ outf) {
  __shared__ ChainSm sm;
  __shared__ float zred[128 * 5];
  __shared__ float esf2[128], bbf2[128], sigl2[64];
  int t = threadIdx.x, bs = blockIdx.x;
  int b = bs >> 10, s = bs & 1023;
  int lane = t & 63, g = t >> 6, n0 = g * 8;

  chain_tile<USE_PTST>(sm, b, s, bs, xyzt, ptst, points, nxf, ballidx,
                       w0, b0, s0, t0, w1, b1, s1, t1, w2, b2, s2, t2,
                       m0w, m0b, m0s, m0t, m1w, m1b, m1s, m1t);

  __syncthreads();                         // done reading m1w
  stage_w64(sm.Wbuf, ew, t);               // rows 0..63
  if (t < 128) { float v = es[t]; esf2[t] = v; bbf2[t] = v * eb[t] + et[t]; }
  if (t < 64) sigl2[t] = sig[b * 64 + t];
  __syncthreads();
  { // gate X in place (own rows)
#pragma unroll
    for (int nj = 0; nj < 8; ++nj)
      sm.X[(n0 + nj) * XS_ + lane] *= sigl2[lane];
  }
  final_half(sm.Wbuf, sm.X, esf2, bbf2, zred, 0, lane, g, n0);
  __syncthreads();
  stage_w64(sm.Wbuf, ew + 64 * 64, t);     // rows 64..127
  __syncthreads();
  final_half(sm.Wbuf, sm.X, esf2, bbf2, zred, 64, lane, g, n0);
  __syncthreads();
  if (t < 128) {
    float m = fmaxf(fmaxf(zred[t * 5 + 0], zred[t * 5 + 1]),
                    fmaxf(zred[t * 5 + 2], zred[t * 5 + 3]));
    outf[((size_t)b * 128 + t) * S_ + s] = nanguard(m);
  }
}

extern "C" void kernel_launch(void* const* d_in, const int* in_sizes, int n_in,
                              void* d_out, int out_size, void* d_ws, size_t ws_size,
                              hipStream_t stream) {
  const float* xyz    = (const float*)d_in[0];
  const float* points = (const float*)d_in[1];
  const float* w0 = (const float*)d_in[2],  *b0 = (const float*)d_in[3],  *s0 = (const float*)d_in[4],  *t0 = (const float*)d_in[5];
  const float* w1 = (const float*)d_in[6],  *b1 = (const float*)d_in[7],  *s1 = (const float*)d_in[8],  *t1 = (const float*)d_in[9];
  const float* w2 = (const float*)d_in[10], *b2 = (const float*)d_in[11], *s2 = (const float*)d_in[12], *t2 = (const float*)d_in[13];
  const float* m0w = (const float*)d_in[14], *m0b = (const float*)d_in[15], *m0s = (const float*)d_in[16], *m0t = (const float*)d_in[17];
  const float* m1w = (const float*)d_in[18], *m1b = (const float*)d_in[19], *m1s = (const float*)d_in[20], *m1t = (const float*)d_in[21];
  const float* ecak = (const float*)d_in[22];
  const float* ew = (const float*)d_in[23], *eb = (const float*)d_in[24], *es = (const float*)d_in[25], *et = (const float*)d_in[26];

  // ---- tiered workspace layout ----
  const size_t OFF_XYZT = 0;                 //  2,097,152 (B,N,4) f32
  const size_t OFF_NXF  = 2097152;           //    262,144 (B,S,4) f32
  const size_t OFF_BIDX = 2359296;           //  2,097,152 (B,S,32) i32
  const size_t OFF_PART = 4456448;           //  4,194,304 (B,S,64) f32
  const size_t OFF_SIG  = 8650752;           //      4,096 (B,64) f32
  const size_t OFF_PTST = 8654848;           // 33,554,432 (B,N,64) f32
  const size_t OFF_H2   = 42209280;          // 134,217,728 (B,S,32,64) f32
  const size_t NEED_PTST = OFF_H2;           // 42,209,280
  const size_t NEED_H2   = 176427008;

  const bool use_ptst = ws_size >= NEED_PTST;
  const bool use_h2   = ws_size >= NEED_H2;

  char* ws = (char*)d_ws;
  float4* xyzt    = (float4*)(ws + OFF_XYZT);
  float4* nxf     = (float4*)(ws + OFF_NXF);
  int*    ballidx = (int*)   (ws + OFF_BIDX);
  float*  partials= (float*) (ws + OFF_PART);
  float*  sig     = (float*) (ws + OFF_SIG);
  float*  ptst    = (float*) (ws + OFF_PTST);
  float*  h2      = (float*) (ws + OFF_H2);

  float* out_xyz  = (float*)d_out;                          // (B,3,S) f32
  float* out_feat = (float*)d_out + (size_t)B_ * 3 * S_;    // (B,128,S) f32

  k_xyzt<<<dim3(N_ / 256, B_), 256, 0, stream>>>(xyz, xyzt);
  if (use_ptst)
    k_ptst<<<dim3(N_ / 64, B_), 256, 0, stream>>>(points, ptst);
  k_fps <<<B_, 1024, 0, stream>>>(xyzt, nxf, out_xyz);
  k_ball<<<(B_ * S_) / 4, 256, 0, stream>>>(xyzt, nxf, ballidx);

  if (use_h2) {
    k_chain<true, true><<<B_ * S_, 256, 0, stream>>>(xyzt, ptst, points, nxf, ballidx,
        w0, b0, s0, t0, w1, b1, s1, t1, w2, b2, s2, t2,
        m0w, m0b, m0s, m0t, m1w, m1b, m1s, m1t, h2, partials);
    k_eca<<<B_, 256, 0, stream>>>(partials, ecak, sig);
    k_final_h2<<<B_ * S_, 256, 0, stream>>>(h2, sig, ew, eb, es, et, out_feat);
  } else if (use_ptst) {
    k_chain<true, false><<<B_ * S_, 256, 0, stream>>>(xyzt, ptst, points, nxf, ballidx,
        w0, b0, s0, t0, w1, b1, s1, t1, w2, b2, s2, t2,
        m0w, m0b, m0s, m0t, m1w, m1b, m1s, m1t, h2, partials);
    k_eca<<<B_, 256, 0, stream>>>(partials, ecak, sig);
    k_final_rec<true><<<B_ * S_, 256, 0, stream>>>(xyzt, ptst, points, nxf, ballidx,
        w0, b0, s0, t0, w1, b1, s1, t1, w2, b2, s2, t2,
        m0w, m0b, m0s, m0t, m1w, m1b, m1s, m1t, sig, ew, eb, es, et, out_feat);
  } else {
    k_chain<false, false><<<B_ * S_, 256, 0, stream>>>(xyzt, ptst, points, nxf, ballidx,
        w0, b0, s0, t0, w1, b1, s1, t1, w2, b2, s2, t2,
        m0w, m0b, m0s, m0t, m1w, m1b, m1s, m1t, h2, partials);
    k_eca<<<B_, 256, 0, stream>>>(partials, ecak, sig);
    k_final_rec<false><<<B_ * S_, 256, 0, stream>>>(xyzt, ptst, points, nxf, ballidx,
        w0, b0, s0, t0, w1, b1, s1, t1, w2, b2, s2, t2,
        m0w, m0b, m0s, m0t, m1w, m1b, m1s, m1t, sig, ew, eb, es, et, out_feat);
  }
}

// Round 14
// 1581.310 us; speedup vs baseline: 1.0537x; 1.0537x over previous
//
#include <hip/hip_runtime.h>

typedef unsigned int   u32;
typedef unsigned long long u64;
typedef float pkf2 __attribute__((ext_vector_type(2)));

#define B_  16
#define N_  8192
#define S_  1024
#define NS_ 32
#define XS_ 68   // [n][c] LDS row stride in floats

__device__ __forceinline__ float nanguard(float v) {
  u32 x = __float_as_uint(v);
  if ((x & 0x7F80u) == 0x7F80u) x ^= 0x0080u;
  return __uint_as_float(x);
}

// wave64 max via DPP (rocPRIM pattern)
__device__ __forceinline__ float wave_max_nonneg(float v) {
  int x = __float_as_int(v);
#define DPP_STEP(ctrl) \
  x = __float_as_int(fmaxf(__int_as_float(x), \
      __int_as_float(__builtin_amdgcn_update_dpp(0, x, (ctrl), 0xf, 0xf, true))))
  DPP_STEP(0x111);  // row_shr:1
  DPP_STEP(0x112);  // row_shr:2
  DPP_STEP(0x114);  // row_shr:4
  DPP_STEP(0x118);  // row_shr:8
  DPP_STEP(0x142);  // row_bcast15
  DPP_STEP(0x143);  // row_bcast31
#undef DPP_STEP
  return __int_as_float(__builtin_amdgcn_readlane(x, 63));
}

// ---------------- K0a: xyz (B,3,N) -> (B,N,4) f32 ----------------
__global__ __launch_bounds__(256) void k_xyzt(const float* __restrict__ xyz, float4* __restrict__ xyzt) {
  int b = blockIdx.y;
  int i = blockIdx.x * 256 + threadIdx.x;
  const float* p = xyz + (size_t)b * 3 * N_;
  xyzt[(size_t)b * N_ + i] = make_float4(p[i], p[N_ + i], p[2 * N_ + i], 0.f);
}

// ---------------- K0b: points (B,64,N) -> (B,N,64) f32 ----------------
__global__ __launch_bounds__(256) void k_ptst(const float* __restrict__ pts, float* __restrict__ ptst) {
  __shared__ float tile[64][65];
  int b = blockIdx.y, n0 = blockIdx.x * 64, t = threadIdx.x;
  {
    int c = t >> 2, j0 = (t & 3) * 16;
    const float4* src = (const float4*)(pts + (size_t)b * 64 * N_ + (size_t)c * N_ + n0 + j0);
#pragma unroll
    for (int q = 0; q < 4; ++q) {
      float4 a = src[q];
      tile[c][j0 + 4*q + 0] = a.x; tile[c][j0 + 4*q + 1] = a.y;
      tile[c][j0 + 4*q + 2] = a.z; tile[c][j0 + 4*q + 3] = a.w;
    }
  }
  __syncthreads();
  {
    int n = t >> 2, c0 = (t & 3) * 16;
    float4* dv = (float4*)(ptst + ((size_t)b * N_ + n0 + n) * 64 + c0);
#pragma unroll
    for (int q = 0; q < 4; ++q)
      dv[q] = make_float4(tile[c0 + 4*q + 0][n], tile[c0 + 4*q + 1][n],
                          tile[c0 + 4*q + 2][n], tile[c0 + 4*q + 3][n]);
  }
}

// ---------------- K1: furthest point sampling — 4 waves ----------------
// r14: 256 threads (4 waves, 1/SIMD), 32 pts/thread in 16 pinned pk-pairs.
// Rounds 4-13 showed per-iter cost is gang-locked serial tail x wave count:
// 16-wave barrier + 16-deep atomic + stagger. 4 waves minimizes all three
// while issue/SIMD stays ~const (same math on 1 wave instead of 4).
// Reduction = r12's (best measured): in-thread tree -> DPP -> ballot ->
// single packed atomicMax per wave. Tie-breaks exact as before.
__global__ __launch_bounds__(256)
__attribute__((amdgpu_waves_per_eu(1, 1)))
void k_fps(const float4* __restrict__ xyzt,
           float4* __restrict__ nxf,
           float* __restrict__ out_xyz) {
#pragma clang fp contract(off)
  __shared__ float4 ldsp[N_];       // 128 KB coord cache
  __shared__ u64 slot[4];
  __shared__ int win_hist[S_];
  int b = blockIdx.x, t = threadIdx.x;
  int lane = t & 63;
  const float4* p4 = xyzt + (size_t)b * N_;

  // coalesced global -> LDS
  for (int j = t; j < N_; j += 256) ldsp[j] = p4[j];
  __syncthreads();

  // own 32 contiguous points -> 16 pk pairs (named scalars; no arrays)
  const float4* own = &ldsp[t * 32];
#define DECLPAIR(P) \
  float4 qa##P = own[2*(P)], qb##P = own[2*(P) + 1]; \
  pkf2 px##P = {qa##P.x, qb##P.x}; pkf2 py##P = {qa##P.y, qb##P.y}; \
  pkf2 pz##P = {qa##P.z, qb##P.z}; pkf2 dm##P = {1e10f, 1e10f};
  DECLPAIR(0) DECLPAIR(1) DECLPAIR(2) DECLPAIR(3)
  DECLPAIR(4) DECLPAIR(5) DECLPAIR(6) DECLPAIR(7)
  DECLPAIR(8) DECLPAIR(9) DECLPAIR(10) DECLPAIR(11)
  DECLPAIR(12) DECLPAIR(13) DECLPAIR(14) DECLPAIR(15)
#undef DECLPAIR
#define PIN(P) asm volatile("" : "+v"(px##P), "+v"(py##P), "+v"(pz##P));
  PIN(0) PIN(1) PIN(2) PIN(3) PIN(4) PIN(5) PIN(6) PIN(7)
  PIN(8) PIN(9) PIN(10) PIN(11) PIN(12) PIN(13) PIN(14) PIN(15)
#undef PIN

  if (t == 0) {
    slot[0] = 8191ull;              // winner of "iter 0": dist bits 0, idx 0
    slot[1] = 0; slot[2] = 0; slot[3] = 0;
    win_hist[0] = 0;
  }
  __syncthreads();
  for (int it = 1; it < S_; ++it) {
    u64 w = slot[(it - 1) & 3];
    int widx = 8191 - (int)(w & 0xFFFFFFFFull);
    if (t == 0) { win_hist[it - 1] = widx; slot[(it + 1) & 3] = 0; }
    float4 c = ldsp[widx & (N_ - 1)];    // LDS broadcast
    pkf2 cx2 = {c.x, c.x}, cy2 = {c.y, c.y}, cz2 = {c.z, c.z};
    // exact np order per element: (dx*dx + dy*dy) + dz*dz, RNE each op
#define UPDP(P) { \
    pkf2 dx = px##P - cx2; pkf2 dy = py##P - cy2; pkf2 dz = pz##P - cz2; \
    pkf2 xx = dx * dx; pkf2 yy = dy * dy; pkf2 zz = dz * dz; \
    pkf2 ss = xx + yy; pkf2 dd = ss + zz; \
    dm##P.x = fminf(dm##P.x, dd.x); dm##P.y = fminf(dm##P.y, dd.y); }
    UPDP(0) UPDP(1) UPDP(2) UPDP(3) UPDP(4) UPDP(5) UPDP(6) UPDP(7)
    UPDP(8) UPDP(9) UPDP(10) UPDP(11) UPDP(12) UPDP(13) UPDP(14) UPDP(15)
#undef UPDP
    // per-pair winner (strict > keeps lower k = lower index)
#define PWIN(P) \
    float pv##P = dm##P.y > dm##P.x ? dm##P.y : dm##P.x; \
    int   pi##P = dm##P.y > dm##P.x ? (2*(P) + 1) : (2*(P));
    PWIN(0) PWIN(1) PWIN(2) PWIN(3) PWIN(4) PWIN(5) PWIN(6) PWIN(7)
    PWIN(8) PWIN(9) PWIN(10) PWIN(11) PWIN(12) PWIN(13) PWIN(14) PWIN(15)
#undef PWIN
#define T2(O, A, B) \
    float v##O = pv##B > pv##A ? pv##B : pv##A; \
    int   j##O = pv##B > pv##A ? pi##B : pi##A;
    T2(a0, 0, 1)  T2(a1, 2, 3)  T2(a2, 4, 5)  T2(a3, 6, 7)
    T2(a4, 8, 9)  T2(a5, 10, 11) T2(a6, 12, 13) T2(a7, 14, 15)
#undef T2
#define T3(O, A, B) \
    float v##O = v##B > v##A ? v##B : v##A; \
    int   j##O = v##B > v##A ? j##B : j##A;
    T3(b0, a0, a1) T3(b1, a2, a3) T3(b2, a4, a5) T3(b3, a6, a7)
    T3(c0, b0, b1) T3(c1, b2, b3)
    T3(z, c0, c1)
#undef T3
    float bv = vz; int bi = t * 32 + jz;
    // wave argmax: DPP max + first lane holding it (== smallest idx)
    float wm = wave_max_nonneg(bv);
    u64 msk = __ballot(bv == wm);
    int wl = __ffsll((long long)msk) - 1;
    int wbi = __builtin_amdgcn_readlane(bi, wl);
    if (lane == 0)
      atomicMax(&slot[it & 3],
                ((u64)__float_as_uint(wm) << 32) | (u64)(u32)(8191 - wbi));
    __syncthreads();
  }
  if (t == 0)
    win_hist[S_ - 1] = 8191 - (int)(slot[(S_ - 1) & 3] & 0xFFFFFFFFull);
  __syncthreads();
  for (int j = t; j < S_; j += 256) {
    int wi = win_hist[j] & (N_ - 1);
    float4 c = ldsp[wi];
    nxf[(size_t)b * S_ + j] = c;
    float* o = out_xyz + (size_t)b * 3 * S_;
    o[j] = nanguard(c.x); o[S_ + j] = nanguard(c.y); o[2 * S_ + j] = nanguard(c.z);
  }
}

// ---------------- K2: ball query (first 32 in range, ascending) ----------------
__global__ __launch_bounds__(256) void k_ball(const float4* __restrict__ xyzt,
                                              const float4* __restrict__ nxf,
                                              int* __restrict__ ballidx) {
  int gw = blockIdx.x * 4 + (threadIdx.x >> 6);
  int lane = threadIdx.x & 63;
  int b = gw >> 10, s = gw & 1023;
  float4 c = nxf[(size_t)b * S_ + s];
  const float4* pts = xyzt + (size_t)b * N_;
  int* out = ballidx + (size_t)gw * NS_;
  int cnt = 0, first = 0;
  bool havefirst = false;
  for (int chunk = 0; chunk < N_; chunk += 64) {
    float4 p = pts[chunk + lane];
    float dx = p.x - c.x, dy = p.y - c.y, dz = p.z - c.z;
    float d2 = __fadd_rn(__fadd_rn(__fmul_rn(dx, dx), __fmul_rn(dy, dy)), __fmul_rn(dz, dz));
    bool v = d2 <= 0.04f;
    u64 m = __ballot(v);
    if (m) {
      int pos = cnt + __popcll(m & ((1ull << lane) - 1ull));
      if (v && pos < NS_) out[pos] = chunk + lane;
      if (!havefirst) { first = chunk + (__ffsll((long long)m) - 1); havefirst = true; }
      cnt += __popcll(m);
      if (cnt >= NS_) break;
    }
  }
  if (cnt < NS_) {
    for (int p = cnt + lane; p < NS_; p += 64) out[p] = first;
  }
}

// ---------------- chain machinery: [n][c], single weight slot, in-place X ----
struct ChainSm {
  float Wbuf[64 * XS_];                       // staged: w2 -> m0w -> m1w
  float W1f[64 * 9];
  float W0f[8 * 4];
  float s2f[64], sm0f[64], sm1f[64];
  float bb0[8];
  float bb1[64], bb2[64], bm0[64], bm1[64];
  float X[32 * XS_];                          // [n][c]
  float scratch[384];                         // P8 [0,256), GX [256,384); psum overlay
  int   idx_s[NS_];
};

__device__ __forceinline__ void stage_w64(float* Wbuf, const float* w, int t) {
  int c = t >> 2, q = (t & 3) * 16;
  const float4* src = (const float4*)(w + c * 64 + q);
  float4* dst = (float4*)(Wbuf + c * XS_ + q);
  dst[0] = src[0]; dst[1] = src[1]; dst[2] = src[2]; dst[3] = src[3];
}

// one 64x64 GEMM pass over the wave's 8 n-rows, in-place allowed
template<bool RELU>
__device__ __forceinline__ void gemm64(const float* Wbuf, float* Xb,
                                       const float* scl, const float* bia,
                                       int lane, int n0) {
  float acc[8] = {0,0,0,0,0,0,0,0};
#pragma unroll
  for (int k4 = 0; k4 < 16; ++k4) {
    float4 wq = *(const float4*)&Wbuf[lane * XS_ + k4 * 4];
#pragma unroll
    for (int nj = 0; nj < 8; ++nj) {
      float4 xq = *(const float4*)&Xb[(n0 + nj) * XS_ + k4 * 4];
      acc[nj] += wq.x * xq.x; acc[nj] += wq.y * xq.y;
      acc[nj] += wq.z * xq.z; acc[nj] += wq.w * xq.w;
    }
  }
  float sc = scl[lane], bi = bia[lane];
#pragma unroll
  for (int nj = 0; nj < 8; ++nj) {
    float v = sc * acc[nj] + bi;
    Xb[(n0 + nj) * XS_ + lane] = RELU ? fmaxf(v, 0.f) : v;
  }
}

// chain through mlp1: post-relu f32 result left in sm.X ([n][c])
template<bool USE_PTST>
__device__ __forceinline__ void chain_tile(ChainSm& sm, int b, int s, int bs,
    const float4* xyzt, const float* ptst, const float* points,
    const float4* nxf, const int* ballidx,
    const float* w0, const float* b0, const float* s0, const float* t0,
    const float* w1, const float* b1, const float* s1, const float* t1,
    const float* w2, const float* b2, const float* s2, const float* t2,
    const float* m0w, const float* m0b, const float* m0s, const float* m0t,
    const float* m1w, const float* m1b, const float* m1s, const float* m1t) {
  int t = threadIdx.x, lane = t & 63, g = t >> 6, n0 = g * 8;

  stage_w64(sm.Wbuf, w2, t);
  if (t < 64) {
    float v2 = s2[t];  sm.s2f[t] = v2;  sm.bb2[t] = v2 * b2[t] + t2[t];
    float vm0 = m0s[t]; sm.sm0f[t] = vm0; sm.bm0[t] = vm0 * m0b[t] + m0t[t];
    float vm1 = m1s[t]; sm.sm1f[t] = vm1; sm.bm1[t] = vm1 * m1b[t] + m1t[t];
    float v1 = s1[t];
#pragma unroll
    for (int k = 0; k < 8; ++k) sm.W1f[t * 9 + k] = v1 * w1[t * 8 + k];
    sm.bb1[t] = v1 * b1[t] + t1[t];
  }
  if (t < 8) {
    float v0 = s0[t];
#pragma unroll
    for (int k = 0; k < 3; ++k) sm.W0f[t * 4 + k] = v0 * w0[t * 3 + k];
    sm.bb0[t] = v0 * b0[t] + t0[t];
  }
  if (t < NS_) sm.idx_s[t] = ballidx[(size_t)bs * NS_ + t] & (N_ - 1);
  __syncthreads();                                   // B1

  { // gather points -> X[n][c] rows (wave-own)
    int n = t >> 3, c8 = (t & 7) * 8;
    int pi = sm.idx_s[n];
    if (USE_PTST) {
      const float4* v = (const float4*)(ptst + ((size_t)b * N_ + pi) * 64 + c8);
      float4* xr = (float4*)&sm.X[n * XS_ + c8];
      xr[0] = v[0]; xr[1] = v[1];
    } else {
      const float* pp = points + (size_t)b * 64 * N_ + (size_t)c8 * N_ + pi;
#pragma unroll
      for (int j = 0; j < 8; ++j) sm.X[n * XS_ + c8 + j] = pp[(size_t)j * N_];
    }
  }
  if (t < NS_) { // centered xyz -> GX
    float4 p = xyzt[(size_t)b * N_ + sm.idx_s[t]];
    float4 cc = nxf[(size_t)b * S_ + s];
    float* gx = &sm.scratch[256 + t * 4];
    gx[0] = p.x - cc.x; gx[1] = p.y - cc.y; gx[2] = p.z - cc.z;
  }
  __syncthreads();                                   // B2 (GX cross-wave)

  { // conv0 (8 out, K=3) + bn + relu -> P8[n][cc]
    int n = t >> 3, cc = t & 7;
    const float* gx = &sm.scratch[256 + n * 4];
    float a = sm.bb0[cc];
    a += sm.W0f[cc * 4 + 0] * gx[0];
    a += sm.W0f[cc * 4 + 1] * gx[1];
    a += sm.W0f[cc * 4 + 2] * gx[2];
    sm.scratch[n * 8 + cc] = fmaxf(a, 0.f);
  }
  { // conv1 (64 out, K=8) + bn, residual into X (own rows; no barrier needed)
#pragma unroll
    for (int nj = 0; nj < 8; ++nj) {
      float a = sm.bb1[lane];
      const float* p8 = &sm.scratch[(n0 + nj) * 8];
#pragma unroll
      for (int k = 0; k < 8; ++k) a += sm.W1f[lane * 9 + k] * p8[k];
      sm.X[(n0 + nj) * XS_ + lane] += a;
    }
  }
  gemm64<false>(sm.Wbuf, sm.X, sm.s2f, sm.bb2, lane, n0);   // conv2
  __syncthreads();                                   // B3 (done reading w2)
  stage_w64(sm.Wbuf, m0w, t);
  __syncthreads();                                   // B4
  gemm64<true>(sm.Wbuf, sm.X, sm.sm0f, sm.bm0, lane, n0);   // mlp0
  __syncthreads();                                   // B5 (done reading m0w)
  stage_w64(sm.Wbuf, m1w, t);
  __syncthreads();                                   // B6
  gemm64<true>(sm.Wbuf, sm.X, sm.sm1f, sm.bm1, lane, n0);   // mlp1 -> X
}

// ---------------- K3: chain pass -> partials (+ optional h2 f32) ----------------
template<bool USE_PTST, bool WRITE_H2>
__global__ __launch_bounds__(256) void k_chain(
    const float4* __restrict__ xyzt, const float* __restrict__ ptst,
    const float* __restrict__ points,
    const float4* __restrict__ nxf, const int* __restrict__ ballidx,
    const float* w0, const float* b0, const float* s0, const float* t0,
    const float* w1, const float* b1, const float* s1, const float* t1,
    const float* w2, const float* b2, const float* s2, const float* t2,
    const float* m0w, const float* m0b, const float* m0s, const float* m0t,
    const float* m1w, const float* m1b, const float* m1s, const float* m1t,
    float* __restrict__ h2out, float* __restrict__ partials) {
  __shared__ ChainSm sm;
  int t = threadIdx.x, bs = blockIdx.x;
  int b = bs >> 10, s = bs & 1023;
  int lane = t & 63, g = t >> 6, n0 = g * 8;

  chain_tile<USE_PTST>(sm, b, s, bs, xyzt, ptst, points, nxf, ballidx,
                       w0, b0, s0, t0, w1, b1, s1, t1, w2, b2, s2, t2,
                       m0w, m0b, m0s, m0t, m1w, m1b, m1s, m1t);

  float* psum = sm.scratch;   // P8/GX dead (all waves past B3)
  float lsum = 0.f;
#pragma unroll
  for (int nj = 0; nj < 8; ++nj) {
    float r = sm.X[(n0 + nj) * XS_ + lane];
    lsum += r;
    if (WRITE_H2)
      h2out[((size_t)bs * 32 + n0 + nj) * 64 + lane] = r;
  }
  psum[lane * 5 + g] = lsum;
  __syncthreads();                                   // B7
  if (t < 64) {
    float v = (psum[t * 5 + 0] + psum[t * 5 + 1]) + (psum[t * 5 + 2] + psum[t * 5 + 3]);
    partials[(size_t)bs * 64 + t] = v;
  }
}

// ---------------- K4: mean + ECA conv + sigmoid -> sig (B,64) ----------------
__global__ __launch_bounds__(256) void k_eca(const float* __restrict__ partials,
                                             const float* __restrict__ ecak,
                                             float* __restrict__ sig) {
  __shared__ float red[64 * 5];
  __shared__ float yy[66];
  int b = blockIdx.x, t = threadIdx.x;
  int c = t & 63, sg = t >> 6;
  float acc = 0.f;
  for (int s = sg; s < S_; s += 4) acc += partials[((size_t)b * S_ + s) * 64 + c];
  red[c * 5 + sg] = acc;
  __syncthreads();
  if (t < 64) {
    float v = (red[t * 5 + 0] + red[t * 5 + 1]) + (red[t * 5 + 2] + red[t * 5 + 3]);
    yy[t + 1] = v * (1.f / 32768.f);
  }
  if (t == 64) { yy[0] = 0.f; yy[65] = 0.f; }
  __syncthreads();
  if (t < 64) {
    float gv = ecak[0] * yy[t] + ecak[1] * yy[t + 1] + ecak[2] * yy[t + 2];
    sig[b * 64 + t] = 1.f / (1.f + expf(-gv));
  }
}

// one 64-output-row half of the final conv
__device__ __forceinline__ void final_half(const float* W, const float* X2,
                                           const float* esf, const float* bbf,
                                           float* zred, int off, int lane, int g, int n0) {
  float a[8] = {0,0,0,0,0,0,0,0};
#pragma unroll
  for (int k4 = 0; k4 < 16; ++k4) {
    float4 wq = *(const float4*)&W[lane * XS_ + k4 * 4];
#pragma unroll
    for (int nj = 0; nj < 8; ++nj) {
      float4 xq = *(const float4*)&X2[(n0 + nj) * XS_ + k4 * 4];
      a[nj] += wq.x * xq.x; a[nj] += wq.y * xq.y;
      a[nj] += wq.z * xq.z; a[nj] += wq.w * xq.w;
    }
  }
  float m = a[0];
#pragma unroll
  for (int j = 1; j < 8; ++j) m = fmaxf(m, a[j]);
  // bn scale > 0, f32 affine monotone -> affine(max)==max(affine)
  zred[(lane + off) * 5 + g] = esf[lane + off] * m + bbf[lane + off];
}

// ---------------- K5a: fast final (reads stored h2 (bs,n,c)) ----------------
__global__ __launch_bounds__(256) void k_final_h2(const float* __restrict__ h2,
                                                  const float* __restrict__ sig,
                                                  const float* ew, const float* eb,
                                                  const float* es, const float* et,
                                                  float* __restrict__ outf) {
  __shared__ float Wb[64 * XS_];
  __shared__ float X2[32 * XS_];
  __shared__ float zred[128 * 5];
  __shared__ float esf[128], bbf[128], sigl[64];
  int t = threadIdx.x, bs = blockIdx.x;
  int b = bs >> 10, s = bs & 1023;
  int lane = t & 63, g = t >> 6, n0 = g * 8;
  stage_w64(Wb, ew, t);                    // rows 0..63
  if (t < 128) { float v = es[t]; esf[t] = v; bbf[t] = v * eb[t] + et[t]; }
  if (t < 64) sigl[t] = sig[b * 64 + t];
  __syncthreads();
  { // gather + gate -> X2 (own rows)
    int n = t >> 3, c8 = (t & 7) * 8;
    const float4* v = (const float4*)(h2 + ((size_t)bs * 32 + n) * 64 + c8);
    float4 a = v[0], bq = v[1];
    a.x *= sigl[c8 + 0]; a.y *= sigl[c8 + 1]; a.z *= sigl[c8 + 2]; a.w *= sigl[c8 + 3];
    bq.x *= sigl[c8 + 4]; bq.y *= sigl[c8 + 5]; bq.z *= sigl[c8 + 6]; bq.w *= sigl[c8 + 7];
    float4* xr = (float4*)&X2[n * XS_ + c8];
    xr[0] = a; xr[1] = bq;
  }
  final_half(Wb, X2, esf, bbf, zred, 0, lane, g, n0);
  __syncthreads();                          // done reading rows 0..63
  stage_w64(Wb, ew + 64 * 64, t);          // rows 64..127
  __syncthreads();
  final_half(Wb, X2, esf, bbf, zred, 64, lane, g, n0);
  __syncthreads();
  if (t < 128) {
    float m = fmaxf(fmaxf(zred[t * 5 + 0], zred[t * 5 + 1]),
                    fmaxf(zred[t * 5 + 2], zred[t * 5 + 3]));
    outf[((size_t)b * 128 + t) * S_ + s] = nanguard(m);
  }
}

// ---------------- K5b: recompute final (no h2 storage) ----------------
template<bool USE_PTST>
__global__ __launch_bounds__(256) void k_final_rec(
    const float4* __restrict__ xyzt, const float* __restrict__ ptst,
    const float* __restrict__ points,
    const float4* __restrict__ nxf, const int* __restrict__ ballidx,
    const float* w0, const float* b0, const float* s0, const float* t0,
    const float* w1, const float* b1, const float* s1, const float* t1,
    const float* w2, const float* b2, const float* s2, const float* t2,
    const float* m0w, const float* m0b, const float* m0s, const float* m0t,
    const float* m1w, const float* m1b, const float* m1s, const float* m1t,
    const float* __restrict__ sig,
    const float* ew, const float* eb, const float* es, const float* et,
    float* __restrict__ outf) {
  __shared__ ChainSm sm;
  __shared__ float zred[128 * 5];
  __shared__ float esf2[128], bbf2[128], sigl2[64];
  int t = threadIdx.x, bs = blockIdx.x;
  int b = bs >> 10, s = bs & 1023;
  int lane = t & 63, g = t >> 6, n0 = g * 8;

  chain_tile<USE_PTST>(sm, b, s, bs, xyzt, ptst, points, nxf, ballidx,
                       w0, b0, s0, t0, w1, b1, s1, t1, w2, b2, s2, t2,
                       m0w, m0b, m0s, m0t, m1w, m1b, m1s, m1t);

  __syncthreads();                         // done reading m1w
  stage_w64(sm.Wbuf, ew, t);               // rows 0..63
  if (t < 128) { float v = es[t]; esf2[t] = v; bbf2[t] = v * eb[t] + et[t]; }
  if (t < 64) sigl2[t] = sig[b * 64 + t];
  __syncthreads();
  { // gate X in place (own rows)
#pragma unroll
    for (int nj = 0; nj < 8; ++nj)
      sm.X[(n0 + nj) * XS_ + lane] *= sigl2[lane];
  }
  final_half(sm.Wbuf, sm.X, esf2, bbf2, zred, 0, lane, g, n0);
  __syncthreads();
  stage_w64(sm.Wbuf, ew + 64 * 64, t);     // rows 64..127
  __syncthreads();
  final_half(sm.Wbuf, sm.X, esf2, bbf2, zred, 64, lane, g, n0);
  __syncthreads();
  if (t < 128) {
    float m = fmaxf(fmaxf(zred[t * 5 + 0], zred[t * 5 + 1]),
                    fmaxf(zred[t * 5 + 2], zred[t * 5 + 3]));
    outf[((size_t)b * 128 + t) * S_ + s] = nanguard(m);
  }
}

extern "C" void kernel_launch(void* const* d_in, const int* in_sizes, int n_in,
                              void* d_out, int out_size, void* d_ws, size_t ws_size,
                              hipStream_t stream) {
  const float* xyz    = (const float*)d_in[0];
  const float* points = (const float*)d_in[1];
  const float* w0 = (const float*)d_in[2],  *b0 = (const float*)d_in[3],  *s0 = (const float*)d_in[4],  *t0 = (const float*)d_in[5];
  const float* w1 = (const float*)d_in[6],  *b1 = (const float*)d_in[7],  *s1 = (const float*)d_in[8],  *t1 = (const float*)d_in[9];
  const float* w2 = (const float*)d_in[10], *b2 = (const float*)d_in[11], *s2 = (const float*)d_in[12], *t2 = (const float*)d_in[13];
  const float* m0w = (const float*)d_in[14], *m0b = (const float*)d_in[15], *m0s = (const float*)d_in[16], *m0t = (const float*)d_in[17];
  const float* m1w = (const float*)d_in[18], *m1b = (const float*)d_in[19], *m1s = (const float*)d_in[20], *m1t = (const float*)d_in[21];
  const float* ecak = (const float*)d_in[22];
  const float* ew = (const float*)d_in[23], *eb = (const float*)d_in[24], *es = (const float*)d_in[25], *et = (const float*)d_in[26];

  // ---- tiered workspace layout ----
  const size_t OFF_XYZT = 0;                 //  2,097,152 (B,N,4) f32
  const size_t OFF_NXF  = 2097152;           //    262,144 (B,S,4) f32
  const size_t OFF_BIDX = 2359296;           //  2,097,152 (B,S,32) i32
  const size_t OFF_PART = 4456448;           //  4,194,304 (B,S,64) f32
  const size_t OFF_SIG  = 8650752;           //      4,096 (B,64) f32
  const size_t OFF_PTST = 8654848;           // 33,554,432 (B,N,64) f32
  const size_t OFF_H2   = 42209280;          // 134,217,728 (B,S,32,64) f32
  const size_t NEED_PTST = OFF_H2;           // 42,209,280
  const size_t NEED_H2   = 176427008;

  const bool use_ptst = ws_size >= NEED_PTST;
  const bool use_h2   = ws_size >= NEED_H2;

  char* ws = (char*)d_ws;
  float4* xyzt    = (float4*)(ws + OFF_XYZT);
  float4* nxf     = (float4*)(ws + OFF_NXF);
  int*    ballidx = (int*)   (ws + OFF_BIDX);
  float*  partials= (float*) (ws + OFF_PART);
  float*  sig     = (float*) (ws + OFF_SIG);
  float*  ptst    = (float*) (ws + OFF_PTST);
  float*  h2      = (float*) (ws + OFF_H2);

  float* out_xyz  = (float*)d_out;                          // (B,3,S) f32
  float* out_feat = (float*)d_out + (size_t)B_ * 3 * S_;    // (B,128,S) f32

  k_xyzt<<<dim3(N_ / 256, B_), 256, 0, stream>>>(xyz, xyzt);
  if (use_ptst)
    k_ptst<<<dim3(N_ / 64, B_), 256, 0, stream>>>(points, ptst);
  k_fps <<<B_, 256, 0, stream>>>(xyzt, nxf, out_xyz);
  k_ball<<<(B_ * S_) / 4, 256, 0, stream>>>(xyzt, nxf, ballidx);

  if (use_h2) {
    k_chain<true, true><<<B_ * S_, 256, 0, stream>>>(xyzt, ptst, points, nxf, ballidx,
        w0, b0, s0, t0, w1, b1, s1, t1, w2, b2, s2, t2,
        m0w, m0b, m0s, m0t, m1w, m1b, m1s, m1t, h2, partials);
    k_eca<<<B_, 256, 0, stream>>>(partials, ecak, sig);
    k_final_h2<<<B_ * S_, 256, 0, stream>>>(h2, sig, ew, eb, es, et, out_feat);
  } else if (use_ptst) {
    k_chain<true, false><<<B_ * S_, 256, 0, stream>>>(xyzt, ptst, points, nxf, ballidx,
        w0, b0, s0, t0, w1, b1, s1, t1, w2, b2, s2, t2,
        m0w, m0b, m0s, m0t, m1w, m1b, m1s, m1t, h2, partials);
    k_eca<<<B_, 256, 0, stream>>>(partials, ecak, sig);
    k_final_rec<true><<<B_ * S_, 256, 0, stream>>>(xyzt, ptst, points, nxf, ballidx,
        w0, b0, s0, t0, w1, b1, s1, t1, w2, b2, s2, t2,
        m0w, m0b, m0s, m0t, m1w, m1b, m1s, m1t, sig, ew, eb, es, et, out_feat);
  } else {
    k_chain<false, false><<<B_ * S_, 256, 0, stream>>>(xyzt, ptst, points, nxf, ballidx,
        w0, b0, s0, t0, w1, b1, s1, t1, w2, b2, s2, t2,
        m0w, m0b, m0s, m0t, m1w, m1b, m1s, m1t, h2, partials);
    k_eca<<<B_, 256, 0, stream>>>(partials, ecak, sig);
    k_final_rec<false><<<B_ * S_, 256, 0, stream>>>(xyzt, ptst, points, nxf, ballidx,
        w0, b0, s0, t0, w1, b1, s1, t1, w2, b2, s2, t2,
        m0w, m0b, m0s, m0t, m1w, m1b, m1s, m1t, sig, ew, eb, es, et, out_feat);
  }
}

// Round 15
// 1541.013 us; speedup vs baseline: 1.0813x; 1.0261x over previous
//
#include <hip/hip_runtime.h>

typedef unsigned int   u32;
typedef unsigned long long u64;
typedef float pkf2 __attribute__((ext_vector_type(2)));

#define B_  16
#define N_  8192
#define S_  1024
#define NS_ 32
#define XS_ 68   // [n][c] LDS row stride in floats

__device__ __forceinline__ float nanguard(float v) {
  u32 x = __float_as_uint(v);
  if ((x & 0x7F80u) == 0x7F80u) x ^= 0x0080u;
  return __uint_as_float(x);
}

// wave64 max via DPP (rocPRIM pattern)
__device__ __forceinline__ float wave_max_nonneg(float v) {
  int x = __float_as_int(v);
#define DPP_STEP(ctrl) \
  x = __float_as_int(fmaxf(__int_as_float(x), \
      __int_as_float(__builtin_amdgcn_update_dpp(0, x, (ctrl), 0xf, 0xf, true))))
  DPP_STEP(0x111);  // row_shr:1
  DPP_STEP(0x112);  // row_shr:2
  DPP_STEP(0x114);  // row_shr:4
  DPP_STEP(0x118);  // row_shr:8
  DPP_STEP(0x142);  // row_bcast15
  DPP_STEP(0x143);  // row_bcast31
#undef DPP_STEP
  return __int_as_float(__builtin_amdgcn_readlane(x, 63));
}

// ---------------- K0a: xyz (B,3,N) -> (B,N,4) f32 ----------------
__global__ __launch_bounds__(256) void k_xyzt(const float* __restrict__ xyz, float4* __restrict__ xyzt) {
  int b = blockIdx.y;
  int i = blockIdx.x * 256 + threadIdx.x;
  const float* p = xyz + (size_t)b * 3 * N_;
  xyzt[(size_t)b * N_ + i] = make_float4(p[i], p[N_ + i], p[2 * N_ + i], 0.f);
}

// ---------------- K0b: points (B,64,N) -> (B,N,64) f32 ----------------
__global__ __launch_bounds__(256) void k_ptst(const float* __restrict__ pts, float* __restrict__ ptst) {
  __shared__ float tile[64][65];
  int b = blockIdx.y, n0 = blockIdx.x * 64, t = threadIdx.x;
  {
    int c = t >> 2, j0 = (t & 3) * 16;
    const float4* src = (const float4*)(pts + (size_t)b * 64 * N_ + (size_t)c * N_ + n0 + j0);
#pragma unroll
    for (int q = 0; q < 4; ++q) {
      float4 a = src[q];
      tile[c][j0 + 4*q + 0] = a.x; tile[c][j0 + 4*q + 1] = a.y;
      tile[c][j0 + 4*q + 2] = a.z; tile[c][j0 + 4*q + 3] = a.w;
    }
  }
  __syncthreads();
  {
    int n = t >> 2, c0 = (t & 3) * 16;
    float4* dv = (float4*)(ptst + ((size_t)b * N_ + n0 + n) * 64 + c0);
#pragma unroll
    for (int q = 0; q < 4; ++q)
      dv[q] = make_float4(tile[c0 + 4*q + 0][n], tile[c0 + 4*q + 1][n],
                          tile[c0 + 4*q + 2][n], tile[c0 + 4*q + 3][n]);
  }
}

// ---------------- K1: furthest point sampling (r12 verbatim: best = 910us) ----
// 16 waves, LDS coord cache, packed-f32 updates, per-wave packed atomicMax.
// r4-r14 falsification sweep: per-iter ~2150cyc invariant across wave count,
// reduction mechanism, centroid source, VALU width, register residency ->
// serial-latency floor; parked.
__global__ __launch_bounds__(1024)
__attribute__((amdgpu_waves_per_eu(4, 4)))
void k_fps(const float4* __restrict__ xyzt,
           float4* __restrict__ nxf,
           float* __restrict__ out_xyz) {
#pragma clang fp contract(off)
  __shared__ float4 ldsp[N_];       // 128 KB coord cache
  __shared__ u64 slot[4];
  __shared__ int win_hist[S_];
  int b = blockIdx.x, t = threadIdx.x;
  const float4* p4 = xyzt + (size_t)b * N_;
  const float4* pp8 = p4 + t * 8;

  float4 q0 = pp8[0], q1 = pp8[1], q2 = pp8[2], q3 = pp8[3];
  float4 q4 = pp8[4], q5 = pp8[5], q6 = pp8[6], q7 = pp8[7];
  ldsp[t * 8 + 0] = q0; ldsp[t * 8 + 1] = q1; ldsp[t * 8 + 2] = q2; ldsp[t * 8 + 3] = q3;
  ldsp[t * 8 + 4] = q4; ldsp[t * 8 + 5] = q5; ldsp[t * 8 + 6] = q6; ldsp[t * 8 + 7] = q7;

#define DECLPAIR(P, A, B) \
  pkf2 px##P = {q##A.x, q##B.x}; pkf2 py##P = {q##A.y, q##B.y}; \
  pkf2 pz##P = {q##A.z, q##B.z}; pkf2 dm##P = {1e10f, 1e10f};
  DECLPAIR(01, 0, 1) DECLPAIR(23, 2, 3) DECLPAIR(45, 4, 5) DECLPAIR(67, 6, 7)
#undef DECLPAIR
#define PIN(P) asm volatile("" : "+v"(px##P), "+v"(py##P), "+v"(pz##P));
  PIN(01) PIN(23) PIN(45) PIN(67)
#undef PIN

  if (t == 0) {
    slot[0] = 8191ull;              // winner of "iter 0": dist bits 0, idx 0
    slot[1] = 0; slot[2] = 0; slot[3] = 0;
    win_hist[0] = 0;
  }
  __syncthreads();
  int lane = t & 63;
  for (int it = 1; it < S_; ++it) {
    u64 w = slot[(it - 1) & 3];
    int widx = 8191 - (int)(w & 0xFFFFFFFFull);
    if (t == 0) { win_hist[it - 1] = widx; slot[(it + 1) & 3] = 0; }
    float4 c = ldsp[widx & (N_ - 1)];    // LDS broadcast
    pkf2 cx2 = {c.x, c.x}, cy2 = {c.y, c.y}, cz2 = {c.z, c.z};
    // exact np order per element: (dx*dx + dy*dy) + dz*dz, RNE each op
#define UPDP(P) { \
    pkf2 dx = px##P - cx2; pkf2 dy = py##P - cy2; pkf2 dz = pz##P - cz2; \
    pkf2 xx = dx * dx; pkf2 yy = dy * dy; pkf2 zz = dz * dz; \
    pkf2 ss = xx + yy; pkf2 dd = ss + zz; \
    dm##P.x = fminf(dm##P.x, dd.x); dm##P.y = fminf(dm##P.y, dd.y); }
    UPDP(01) UPDP(23) UPDP(45) UPDP(67)
#undef UPDP
    float e0 = dm01.x, e1 = dm01.y, e2 = dm23.x, e3 = dm23.y;
    float e4 = dm45.x, e5 = dm45.y, e6 = dm67.x, e7 = dm67.y;
    // pairwise tree, strict > so ties keep lower k
    float va0 = e1 > e0 ? e1 : e0; int ia0 = e1 > e0 ? 1 : 0;
    float va1 = e3 > e2 ? e3 : e2; int ia1 = e3 > e2 ? 3 : 2;
    float va2 = e5 > e4 ? e5 : e4; int ia2 = e5 > e4 ? 5 : 4;
    float va3 = e7 > e6 ? e7 : e6; int ia3 = e7 > e6 ? 7 : 6;
    float vb0 = va1 > va0 ? va1 : va0; int ib0 = va1 > va0 ? ia1 : ia0;
    float vb1 = va3 > va2 ? va3 : va2; int ib1 = va3 > va2 ? ia3 : ia2;
    float bv = vb1 > vb0 ? vb1 : vb0;  int bk = vb1 > vb0 ? ib1 : ib0;
    int bi = t * 8 + bk;
    // wave argmax: DPP max + first lane holding it (== smallest idx)
    float wm = wave_max_nonneg(bv);
    u64 msk = __ballot(bv == wm);
    int wl = __ffsll((long long)msk) - 1;
    int wbi = __builtin_amdgcn_readlane(bi, wl);
    if (lane == 0)
      atomicMax(&slot[it & 3],
                ((u64)__float_as_uint(wm) << 32) | (u64)(u32)(8191 - wbi));
    __syncthreads();
  }
  if (t == 0)
    win_hist[S_ - 1] = 8191 - (int)(slot[(S_ - 1) & 3] & 0xFFFFFFFFull);
  __syncthreads();
  {
    int wi = win_hist[t] & (N_ - 1);
    float4 c = ldsp[wi];
    nxf[(size_t)b * S_ + t] = c;
    float* o = out_xyz + (size_t)b * 3 * S_;
    o[t] = nanguard(c.x); o[S_ + t] = nanguard(c.y); o[2 * S_ + t] = nanguard(c.z);
  }
}

// ---------------- K2: ball query (first 32 in range, ascending) ----------------
__global__ __launch_bounds__(256) void k_ball(const float4* __restrict__ xyzt,
                                              const float4* __restrict__ nxf,
                                              int* __restrict__ ballidx) {
  int gw = blockIdx.x * 4 + (threadIdx.x >> 6);
  int lane = threadIdx.x & 63;
  int b = gw >> 10, s = gw & 1023;
  float4 c = nxf[(size_t)b * S_ + s];
  const float4* pts = xyzt + (size_t)b * N_;
  int* out = ballidx + (size_t)gw * NS_;
  int cnt = 0, first = 0;
  bool havefirst = false;
  for (int chunk = 0; chunk < N_; chunk += 64) {
    float4 p = pts[chunk + lane];
    float dx = p.x - c.x, dy = p.y - c.y, dz = p.z - c.z;
    float d2 = __fadd_rn(__fadd_rn(__fmul_rn(dx, dx), __fmul_rn(dy, dy)), __fmul_rn(dz, dz));
    bool v = d2 <= 0.04f;
    u64 m = __ballot(v);
    if (m) {
      int pos = cnt + __popcll(m & ((1ull << lane) - 1ull));
      if (v && pos < NS_) out[pos] = chunk + lane;
      if (!havefirst) { first = chunk + (__ffsll((long long)m) - 1); havefirst = true; }
      cnt += __popcll(m);
      if (cnt >= NS_) break;
    }
  }
  if (cnt < NS_) {
    for (int p = cnt + lane; p < NS_; p += 64) out[p] = first;
  }
}

// ---------------- chain machinery (r10 verbatim: best measured chain) --------
// [n][c] layout, separate X/H buffers, 40,736B -> 3 blocks/CU.
struct ChainSm {
  float Wbuf[64 * XS_];   // staged weights, reused: w2 -> m0w -> m1w
  float W1f[64 * 9];
  float W0f[8 * 4];
  float s2f[64], sm0f[64], sm1f[64];
  float bb0[8];
  float bb1[64], bb2[64], bm0[64], bm1[64];
  float X[32 * XS_];      // [n][c]
  float H[32 * XS_];      // [n][c]
  float scratch[384];     // P8 [0,256), GX [256,384); psum overlay
  int   idx_s[NS_];
};

__device__ __forceinline__ void stage_w64(float* Wbuf, const float* w, int t) {
  int c = t >> 2, q = (t & 3) * 16;
  const float4* src = (const float4*)(w + c * 64 + q);
  float4* dst = (float4*)(Wbuf + c * XS_ + q);
  dst[0] = src[0]; dst[1] = src[1]; dst[2] = src[2]; dst[3] = src[3];
}

// one 64x64 GEMM pass over the wave's 8 n-rows: Yout[n][lane] = affine(acc)
template<bool RELU>
__device__ __forceinline__ void gemm64(const float* __restrict__ Wbuf,
                                       const float* __restrict__ Xin,
                                       float* __restrict__ Yout,
                                       const float* __restrict__ scl,
                                       const float* __restrict__ bia,
                                       int lane, int n0) {
  float acc[8] = {0,0,0,0,0,0,0,0};
#pragma unroll
  for (int k4 = 0; k4 < 16; ++k4) {
    float4 wq = *(const float4*)&Wbuf[lane * XS_ + k4 * 4];
#pragma unroll
    for (int nj = 0; nj < 8; ++nj) {
      float4 xq = *(const float4*)&Xin[(n0 + nj) * XS_ + k4 * 4];
      acc[nj] += wq.x * xq.x; acc[nj] += wq.y * xq.y;
      acc[nj] += wq.z * xq.z; acc[nj] += wq.w * xq.w;
    }
  }
  float sc = scl[lane], bi = bia[lane];
#pragma unroll
  for (int nj = 0; nj < 8; ++nj) {
    float v = sc * acc[nj] + bi;
    Yout[(n0 + nj) * XS_ + lane] = RELU ? fmaxf(v, 0.f) : v;
  }
}

// chain through mlp1: post-relu f32 result left in sm.H ([n][c])
template<bool USE_PTST>
__device__ __forceinline__ void chain_tile(ChainSm& sm, int b, int s, int bs,
    const float4* xyzt, const float* ptst, const float* points,
    const float4* nxf, const int* ballidx,
    const float* w0, const float* b0, const float* s0, const float* t0,
    const float* w1, const float* b1, const float* s1, const float* t1,
    const float* w2, const float* b2, const float* s2, const float* t2,
    const float* m0w, const float* m0b, const float* m0s, const float* m0t,
    const float* m1w, const float* m1b, const float* m1s, const float* m1t) {
  int t = threadIdx.x, lane = t & 63, g = t >> 6, n0 = g * 8;

  stage_w64(sm.Wbuf, w2, t);
  if (t < 64) {
    float v2 = s2[t];  sm.s2f[t] = v2;  sm.bb2[t] = v2 * b2[t] + t2[t];
    float vm0 = m0s[t]; sm.sm0f[t] = vm0; sm.bm0[t] = vm0 * m0b[t] + m0t[t];
    float vm1 = m1s[t]; sm.sm1f[t] = vm1; sm.bm1[t] = vm1 * m1b[t] + m1t[t];
    float v1 = s1[t];
#pragma unroll
    for (int k = 0; k < 8; ++k) sm.W1f[t * 9 + k] = v1 * w1[t * 8 + k];
    sm.bb1[t] = v1 * b1[t] + t1[t];
  }
  if (t < 8) {
    float v0 = s0[t];
#pragma unroll
    for (int k = 0; k < 3; ++k) sm.W0f[t * 4 + k] = v0 * w0[t * 3 + k];
    sm.bb0[t] = v0 * b0[t] + t0[t];
  }
  if (t < NS_) sm.idx_s[t] = ballidx[(size_t)bs * NS_ + t] & (N_ - 1);
  __syncthreads();                                   // B1

  { // gather points -> X[n][c] rows (wave-own)
    int n = t >> 3, c8 = (t & 7) * 8;
    int pi = sm.idx_s[n];
    if (USE_PTST) {
      const float4* v = (const float4*)(ptst + ((size_t)b * N_ + pi) * 64 + c8);
      float4* xr = (float4*)&sm.X[n * XS_ + c8];
      xr[0] = v[0]; xr[1] = v[1];
    } else {
      const float* pp = points + (size_t)b * 64 * N_ + (size_t)c8 * N_ + pi;
#pragma unroll
      for (int j = 0; j < 8; ++j) sm.X[n * XS_ + c8 + j] = pp[(size_t)j * N_];
    }
  }
  if (t < NS_) { // centered xyz -> GX
    float4 p = xyzt[(size_t)b * N_ + sm.idx_s[t]];
    float4 cc = nxf[(size_t)b * S_ + s];
    float* gx = &sm.scratch[256 + t * 4];
    gx[0] = p.x - cc.x; gx[1] = p.y - cc.y; gx[2] = p.z - cc.z;
  }
  __syncthreads();                                   // B2 (GX cross-wave)

  { // conv0 (8 out, K=3) + bn + relu -> P8[n][cc]
    int n = t >> 3, cc = t & 7;
    const float* gx = &sm.scratch[256 + n * 4];
    float a = sm.bb0[cc];
    a += sm.W0f[cc * 4 + 0] * gx[0];
    a += sm.W0f[cc * 4 + 1] * gx[1];
    a += sm.W0f[cc * 4 + 2] * gx[2];
    sm.scratch[n * 8 + cc] = fmaxf(a, 0.f);
  }
  { // conv1 (64 out, K=8) + bn, residual into X (own rows; no barrier needed)
#pragma unroll
    for (int nj = 0; nj < 8; ++nj) {
      float a = sm.bb1[lane];
      const float* p8 = &sm.scratch[(n0 + nj) * 8];
#pragma unroll
      for (int k = 0; k < 8; ++k) a += sm.W1f[lane * 9 + k] * p8[k];
      sm.X[(n0 + nj) * XS_ + lane] += a;
    }
  }
  gemm64<false>(sm.Wbuf, sm.X, sm.H, sm.s2f, sm.bb2, lane, n0);   // conv2
  __syncthreads();                                   // B3 (done reading w2)
  stage_w64(sm.Wbuf, m0w, t);
  __syncthreads();                                   // B4
  gemm64<true>(sm.Wbuf, sm.H, sm.X, sm.sm0f, sm.bm0, lane, n0);   // mlp0
  __syncthreads();                                   // B5 (done reading m0w)
  stage_w64(sm.Wbuf, m1w, t);
  __syncthreads();                                   // B6
  gemm64<true>(sm.Wbuf, sm.X, sm.H, sm.sm1f, sm.bm1, lane, n0);   // mlp1 -> H
}

// ---------------- K3: chain pass -> partials (+ optional h2 f32) ----------------
template<bool USE_PTST, bool WRITE_H2>
__global__ __launch_bounds__(256) void k_chain(
    const float4* __restrict__ xyzt, const float* __restrict__ ptst,
    const float* __restrict__ points,
    const float4* __restrict__ nxf, const int* __restrict__ ballidx,
    const float* w0, const float* b0, const float* s0, const float* t0,
    const float* w1, const float* b1, const float* s1, const float* t1,
    const float* w2, const float* b2, const float* s2, const float* t2,
    const float* m0w, const float* m0b, const float* m0s, const float* m0t,
    const float* m1w, const float* m1b, const float* m1s, const float* m1t,
    float* __restrict__ h2out, float* __restrict__ partials) {
  __shared__ ChainSm sm;
  int t = threadIdx.x, bs = blockIdx.x;
  int b = bs >> 10, s = bs & 1023;
  int lane = t & 63, g = t >> 6, n0 = g * 8;

  chain_tile<USE_PTST>(sm, b, s, bs, xyzt, ptst, points, nxf, ballidx,
                       w0, b0, s0, t0, w1, b1, s1, t1, w2, b2, s2, t2,
                       m0w, m0b, m0s, m0t, m1w, m1b, m1s, m1t);

  float* psum = sm.scratch;   // P8/GX dead (all waves past B3)
  float lsum = 0.f;
#pragma unroll
  for (int nj = 0; nj < 8; ++nj) {
    float r = sm.H[(n0 + nj) * XS_ + lane];
    lsum += r;
    if (WRITE_H2)
      h2out[((size_t)bs * 32 + n0 + nj) * 64 + lane] = r;
  }
  psum[lane * 5 + g] = lsum;
  __syncthreads();                                   // B7
  if (t < 64) {
    float v = (psum[t * 5 + 0] + psum[t * 5 + 1]) + (psum[t * 5 + 2] + psum[t * 5 + 3]);
    partials[(size_t)bs * 64 + t] = v;
  }
}

// ---------------- K4: mean + ECA conv + sigmoid -> sig (B,64) ----------------
__global__ __launch_bounds__(256) void k_eca(const float* __restrict__ partials,
                                             const float* __restrict__ ecak,
                                             float* __restrict__ sig) {
  __shared__ float red[64 * 5];
  __shared__ float yy[66];
  int b = blockIdx.x, t = threadIdx.x;
  int c = t & 63, sg = t >> 6;
  float acc = 0.f;
  for (int s = sg; s < S_; s += 4) acc += partials[((size_t)b * S_ + s) * 64 + c];
  red[c * 5 + sg] = acc;
  __syncthreads();
  if (t < 64) {
    float v = (red[t * 5 + 0] + red[t * 5 + 1]) + (red[t * 5 + 2] + red[t * 5 + 3]);
    yy[t + 1] = v * (1.f / 32768.f);
  }
  if (t == 64) { yy[0] = 0.f; yy[65] = 0.f; }
  __syncthreads();
  if (t < 64) {
    float gv = ecak[0] * yy[t] + ecak[1] * yy[t + 1] + ecak[2] * yy[t + 2];
    sig[b * 64 + t] = 1.f / (1.f + expf(-gv));
  }
}

// dual 64-row GEMM + max epilogue shared by both finals (r10 verbatim)
__device__ __forceinline__ void final_gemm(const float* __restrict__ WA,
                                           const float* __restrict__ WB,
                                           const float* __restrict__ X2,
                                           const float* __restrict__ esf,
                                           const float* __restrict__ bbf,
                                           float* __restrict__ zred,
                                           float* __restrict__ outf,
                                           int b, int s, int t) {
  int lane = t & 63, g = t >> 6, n0 = g * 8;
  float aA[8] = {0,0,0,0,0,0,0,0}, aB[8] = {0,0,0,0,0,0,0,0};
#pragma unroll
  for (int k4 = 0; k4 < 16; ++k4) {
    float4 wqA = *(const float4*)&WA[lane * XS_ + k4 * 4];
    float4 wqB = *(const float4*)&WB[lane * XS_ + k4 * 4];
#pragma unroll
    for (int nj = 0; nj < 8; ++nj) {
      float4 xq = *(const float4*)&X2[(n0 + nj) * XS_ + k4 * 4];
      aA[nj] += wqA.x * xq.x; aA[nj] += wqA.y * xq.y;
      aA[nj] += wqA.z * xq.z; aA[nj] += wqA.w * xq.w;
      aB[nj] += wqB.x * xq.x; aB[nj] += wqB.y * xq.y;
      aB[nj] += wqB.z * xq.z; aB[nj] += wqB.w * xq.w;
    }
  }
  float mA = aA[0], mB = aB[0];
#pragma unroll
  for (int j = 1; j < 8; ++j) { mA = fmaxf(mA, aA[j]); mB = fmaxf(mB, aB[j]); }
  // bn scale > 0, f32 affine monotone -> affine(max)==max(affine)
  zred[lane * 5 + g]        = esf[lane] * mA + bbf[lane];
  zred[(lane + 64) * 5 + g] = esf[lane + 64] * mB + bbf[lane + 64];
  __syncthreads();
  if (t < 128) {
    float m = fmaxf(fmaxf(zred[t * 5 + 0], zred[t * 5 + 1]),
                    fmaxf(zred[t * 5 + 2], zred[t * 5 + 3]));
    outf[((size_t)b * 128 + t) * S_ + s] = nanguard(m);
  }
}

// ---------------- K5a: fast final (reads stored h2, (bs,n,c)) ----------------
__global__ __launch_bounds__(256) void k_final_h2(const float* __restrict__ h2,
                                                  const float* __restrict__ sig,
                                                  const float* ew, const float* eb,
                                                  const float* es, const float* et,
                                                  float* __restrict__ outf) {
  __shared__ float Wh[128 * XS_];
  __shared__ float esf[128], bbf[128], sigl[64];
  __shared__ float X2[32 * XS_];
  __shared__ float zred[128 * 5];
  int t = threadIdx.x, bs = blockIdx.x;
  int b = bs >> 10, s = bs & 1023;
  {
    int c2 = t >> 1, h = (t & 1) * 32;
    const float4* src = (const float4*)(ew + c2 * 64 + h);
    float4* dst = (float4*)(Wh + c2 * XS_ + h);
#pragma unroll
    for (int j = 0; j < 8; ++j) dst[j] = src[j];
  }
  if (t < 128) {
    float v = es[t]; esf[t] = v; bbf[t] = v * eb[t] + et[t];
  }
  if (t < 64) sigl[t] = sig[b * 64 + t];
  __syncthreads();
  { // gather + gate -> X2[n][c] (wave-own rows)
    int n = t >> 3, c8 = (t & 7) * 8;
    const float4* v = (const float4*)(h2 + ((size_t)bs * 32 + n) * 64 + c8);
    float4 a = v[0], bq = v[1];
    a.x *= sigl[c8 + 0]; a.y *= sigl[c8 + 1]; a.z *= sigl[c8 + 2]; a.w *= sigl[c8 + 3];
    bq.x *= sigl[c8 + 4]; bq.y *= sigl[c8 + 5]; bq.z *= sigl[c8 + 6]; bq.w *= sigl[c8 + 7];
    float4* xr = (float4*)&X2[n * XS_ + c8];
    xr[0] = a; xr[1] = bq;
  }
  // X2 rows wave-own -> no barrier before GEMM
  final_gemm(Wh, Wh + 64 * XS_, X2, esf, bbf, zred, outf, b, s, t);
}

// ---------------- K5b: recompute final (no h2 storage) ----------------
template<bool USE_PTST>
__global__ __launch_bounds__(256) void k_final_rec(
    const float4* __restrict__ xyzt, const float* __restrict__ ptst,
    const float* __restrict__ points,
    const float4* __restrict__ nxf, const int* __restrict__ ballidx,
    const float* w0, const float* b0, const float* s0, const float* t0,
    const float* w1, const float* b1, const float* s1, const float* t1,
    const float* w2, const float* b2, const float* s2, const float* t2,
    const float* m0w, const float* m0b, const float* m0s, const float* m0t,
    const float* m1w, const float* m1b, const float* m1s, const float* m1t,
    const float* __restrict__ sig,
    const float* ew, const float* eb, const float* es, const float* et,
    float* __restrict__ outf) {
  __shared__ ChainSm sm;
  __shared__ float Wb2[64 * XS_];
  __shared__ float esf2[128], bbf2[128], sigl2[64];
  __shared__ float zred[128 * 5];
  int t = threadIdx.x, bs = blockIdx.x;
  int b = bs >> 10, s = bs & 1023;
  int lane = t & 63, g = t >> 6, n0 = g * 8;

  chain_tile<USE_PTST>(sm, b, s, bs, xyzt, ptst, points, nxf, ballidx,
                       w0, b0, s0, t0, w1, b1, s1, t1, w2, b2, s2, t2,
                       m0w, m0b, m0s, m0t, m1w, m1b, m1s, m1t);

  __syncthreads();  // all waves done reading m1w before Wbuf is re-staged
  stage_w64(sm.Wbuf, ew, t);             // rows 0..63
  stage_w64(Wb2, ew + 64 * 64, t);       // rows 64..127
  if (t < 128) {
    float v = es[t]; esf2[t] = v; bbf2[t] = v * eb[t] + et[t];
  }
  if (t < 64) sigl2[t] = sig[b * 64 + t];
  __syncthreads();
  { // gate H -> X (wave-own rows)
#pragma unroll
    for (int nj = 0; nj < 8; ++nj)
      sm.X[(n0 + nj) * XS_ + lane] = sigl2[lane] * sm.H[(n0 + nj) * XS_ + lane];
  }
  final_gemm(sm.Wbuf, Wb2, sm.X, esf2, bbf2, zred, outf, b, s, t);
}

extern "C" void kernel_launch(void* const* d_in, const int* in_sizes, int n_in,
                              void* d_out, int out_size, void* d_ws, size_t ws_size,
                              hipStream_t stream) {
  const float* xyz    = (const float*)d_in[0];
  const float* points = (const float*)d_in[1];
  const float* w0 = (const float*)d_in[2],  *b0 = (const float*)d_in[3],  *s0 = (const float*)d_in[4],  *t0 = (const float*)d_in[5];
  const float* w1 = (const float*)d_in[6],  *b1 = (const float*)d_in[7],  *s1 = (const float*)d_in[8],  *t1 = (const float*)d_in[9];
  const float* w2 = (const float*)d_in[10], *b2 = (const float*)d_in[11], *s2 = (const float*)d_in[12], *t2 = (const float*)d_in[13];
  const float* m0w = (const float*)d_in[14], *m0b = (const float*)d_in[15], *m0s = (const float*)d_in[16], *m0t = (const float*)d_in[17];
  const float* m1w = (const float*)d_in[18], *m1b = (const float*)d_in[19], *m1s = (const float*)d_in[20], *m1t = (const float*)d_in[21];
  const float* ecak = (const float*)d_in[22];
  const float* ew = (const float*)d_in[23], *eb = (const float*)d_in[24], *es = (const float*)d_in[25], *et = (const float*)d_in[26];

  // ---- tiered workspace layout ----
  const size_t OFF_XYZT = 0;                 //  2,097,152 (B,N,4) f32
  const size_t OFF_NXF  = 2097152;           //    262,144 (B,S,4) f32
  const size_t OFF_BIDX = 2359296;           //  2,097,152 (B,S,32) i32
  const size_t OFF_PART = 4456448;           //  4,194,304 (B,S,64) f32
  const size_t OFF_SIG  = 8650752;           //      4,096 (B,64) f32
  const size_t OFF_PTST = 8654848;           // 33,554,432 (B,N,64) f32
  const size_t OFF_H2   = 42209280;          // 134,217,728 (B,S,32,64) f32
  const size_t NEED_PTST = OFF_H2;           // 42,209,280
  const size_t NEED_H2   = 176427008;

  const bool use_ptst = ws_size >= NEED_PTST;
  const bool use_h2   = ws_size >= NEED_H2;

  char* ws = (char*)d_ws;
  float4* xyzt    = (float4*)(ws + OFF_XYZT);
  float4* nxf     = (float4*)(ws + OFF_NXF);
  int*    ballidx = (int*)   (ws + OFF_BIDX);
  float*  partials= (float*) (ws + OFF_PART);
  float*  sig     = (float*) (ws + OFF_SIG);
  float*  ptst    = (float*) (ws + OFF_PTST);
  float*  h2      = (float*) (ws + OFF_H2);

  float* out_xyz  = (float*)d_out;                          // (B,3,S) f32
  float* out_feat = (float*)d_out + (size_t)B_ * 3 * S_;    // (B,128,S) f32

  k_xyzt<<<dim3(N_ / 256, B_), 256, 0, stream>>>(xyz, xyzt);
  if (use_ptst)
    k_ptst<<<dim3(N_ / 64, B_), 256, 0, stream>>>(points, ptst);
  k_fps <<<B_, 1024, 0, stream>>>(xyzt, nxf, out_xyz);
  k_ball<<<(B_ * S_) / 4, 256, 0, stream>>>(xyzt, nxf, ballidx);

  if (use_h2) {
    k_chain<true, true><<<B_ * S_, 256, 0, stream>>>(xyzt, ptst, points, nxf, ballidx,
        w0, b0, s0, t0, w1, b1, s1, t1, w2, b2, s2, t2,
        m0w, m0b, m0s, m0t, m1w, m1b, m1s, m1t, h2, partials);
    k_eca<<<B_, 256, 0, stream>>>(partials, ecak, sig);
    k_final_h2<<<B_ * S_, 256, 0, stream>>>(h2, sig, ew, eb, es, et, out_feat);
  } else if (use_ptst) {
    k_chain<true, false><<<B_ * S_, 256, 0, stream>>>(xyzt, ptst, points, nxf, ballidx,
        w0, b0, s0, t0, w1, b1, s1, t1, w2, b2, s2, t2,
        m0w, m0b, m0s, m0t, m1w, m1b, m1s, m1t, h2, partials);
    k_eca<<<B_, 256, 0, stream>>>(partials, ecak, sig);
    k_final_rec<true><<<B_ * S_, 256, 0, stream>>>(xyzt, ptst, points, nxf, ballidx,
        w0, b0, s0, t0, w1, b1, s1, t1, w2, b2, s2, t2,
        m0w, m0b, m0s, m0t, m1w, m1b, m1s, m1t, sig, ew, eb, es, et, out_feat);
  } else {
    k_chain<false, false><<<B_ * S_, 256, 0, stream>>>(xyzt, ptst, points, nxf, ballidx,
        w0, b0, s0, t0, w1, b1, s1, t1, w2, b2, s2, t2,
        m0w, m0b, m0s, m0t, m1w, m1b, m1s, m1t, h2, partials);
    k_eca<<<B_, 256, 0, stream>>>(partials, ecak, sig);
    k_final_rec<false><<<B_ * S_, 256, 0, stream>>>(xyzt, ptst, points, nxf, ballidx,
        w0, b0, s0, t0, w1, b1, s1, t1, w2, b2, s2, t2,
        m0w, m0b, m0s, m0t, m1w, m1b, m1s, m1t, sig, ew, eb, es, et, out_feat);
  }
}